// Round 4
// baseline (14357.584 us; speedup 1.0000x reference)
//
#include <hip/hip_runtime.h>
#include <hip/hip_cooperative_groups.h>
#include <math.h>

namespace {
constexpr int B_ = 128;
constexpr int T_ = 256;
constexpr int D_ = 512;
constexpr int U_ = 1024;
constexpr int N3U = 3 * U_;        // 3072
constexpr int K_TOT = D_ + U_;     // 1536
}

#define E_CONST 2.71828182845904523536f

using bf16x8 = __attribute__((ext_vector_type(8))) short;
using f32x4  = __attribute__((ext_vector_type(4))) float;

__device__ inline unsigned short f2bf(float f) {
    union { float f; unsigned int u; } a; a.f = f;
    unsigned int u = a.u;
    return (unsigned short)((u + 0x7FFFu + ((u >> 16) & 1u)) >> 16);  // RNE
}

__device__ inline bf16x8 ldb16(const unsigned short* p) {
    return *reinterpret_cast<const bf16x8*>(p);
}

__device__ inline bf16x8 cvt8(const float* src) {
    float v[8];
    *reinterpret_cast<float4*>(&v[0]) = *reinterpret_cast<const float4*>(src);
    *reinterpret_cast<float4*>(&v[4]) = *reinterpret_cast<const float4*>(src + 4);
    bf16x8 r;
    #pragma unroll
    for (int j = 0; j < 8; ++j) r[j] = (short)f2bf(v[j]);
    return r;
}

// ---- one-time prep: WcatT[n][k] = bf16( k<512 ? Wk[k][n] : Wr[k-512][n] ) ----
__global__ void wprep(const float* __restrict__ Wk, const float* __restrict__ Wr,
                      unsigned short* __restrict__ WcatT) {
    __shared__ unsigned short S[32][33];
    const int kb = blockIdx.x * 32;
    const int nb = blockIdx.y * 32;
    const int tx = threadIdx.x;   // 0..31
    const int ty = threadIdx.y;   // 0..7
    #pragma unroll
    for (int j = 0; j < 4; ++j) {
        const int r = ty + 8 * j;         // k-local
        const int k = kb + r;
        const int n = nb + tx;
        const float v = (k < D_) ? Wk[(size_t)k * N3U + n]
                                 : Wr[(size_t)(k - D_) * N3U + n];
        S[tx][r] = f2bf(v);               // transposed store: S[n-local][k-local]
    }
    __syncthreads();
    #pragma unroll
    for (int j = 0; j < 4; ++j) {
        const int r = ty + 8 * j;         // n-local
        WcatT[(size_t)(nb + r) * K_TOT + kb + tx] = S[r][tx];
    }
}

// ---- persistent kernel: all T=256 steps with grid-wide sync between steps ----
// grid 64 blocks x 512 threads (8 waves: 4 b-waves x 2 u-waves).
// block: ub = bid>>1 (u-tile of 32), bb = bid&1 (b-tile of 64).
__global__ __launch_bounds__(512) void tgru_persist(
    const float* __restrict__ seq,            // [B,T,D] fp32
    const float* __restrict__ dts,            // [B,T]
    const unsigned short* __restrict__ WcatT, // [3072][1536] bf16
    const float* __restrict__ ib,             // [3U]
    const float* __restrict__ rb,             // [3U]
    unsigned short* hb0, float* hf0,          // ping: h*dec (bf16 / fp32)
    unsigned short* hb1, float* hf1,          // pong
    float* __restrict__ out)                  // [B,U]
{
    cooperative_groups::grid_group grid = cooperative_groups::this_grid();

    const int tid  = threadIdx.x;
    const int lane = tid & 63;
    const int w    = tid >> 6;            // 0..7
    const int wr   = w >> 1;              // 0..3 (b)
    const int wu   = w & 1;               // 0..1 (u)
    const int bid  = blockIdx.x;
    const int ub   = bid >> 1;            // 0..31
    const int bb   = bid & 1;             // 0..1
    const int b_base = bb * 64 + wr * 16;
    const int u_base = ub * 32 + wu * 16;
    const int l15 = lane & 15;
    const int lk  = lane >> 4;            // 0..3
    const int u   = u_base + l15;

    // Hoisted invariants (constant across all timesteps)
    const unsigned short* bpz = WcatT + (size_t)(u)          * K_TOT + 8 * lk;
    const unsigned short* bpr = WcatT + (size_t)(U_ + u)     * K_TOT + 8 * lk;
    const unsigned short* bph = WcatT + (size_t)(2 * U_ + u) * K_TOT + 8 * lk;
    const float bz_s = ib[u]          + rb[u];
    const float br_s = ib[U_ + u]     + rb[U_ + u];
    const float ibh  = ib[2 * U_ + u];
    const float rbh  = rb[2 * U_ + u];

    for (int t = 0; t < T_; ++t) {
        const unsigned short* hbp = (t & 1) ? hb1 : hb0;
        const float*          hfp = (t & 1) ? hf1 : hf0;
        unsigned short*       hbn = (t & 1) ? hb0 : hb1;
        float*                hfn = (t & 1) ? hf0 : hf1;

        f32x4 accz  = {0.f, 0.f, 0.f, 0.f};
        f32x4 accr  = {0.f, 0.f, 0.f, 0.f};
        f32x4 acchx = {0.f, 0.f, 0.f, 0.f};
        f32x4 acchr = {0.f, 0.f, 0.f, 0.f};

        // ---- phase X: k in [0, 512), A = bf16(seq[b][t][k]) ----
        {
            const float* ap = seq + ((size_t)(b_base + l15) * T_ + t) * D_ + 8 * lk;
            #pragma unroll 4
            for (int ks = 0; ks < D_ / 32; ++ks) {
                const bf16x8 a  = cvt8(ap + 32 * ks);
                const bf16x8 bz = ldb16(bpz + 32 * ks);
                const bf16x8 br = ldb16(bpr + 32 * ks);
                const bf16x8 bh = ldb16(bph + 32 * ks);
                accz  = __builtin_amdgcn_mfma_f32_16x16x32_bf16(a, bz, accz,  0, 0, 0);
                accr  = __builtin_amdgcn_mfma_f32_16x16x32_bf16(a, br, accr,  0, 0, 0);
                acchx = __builtin_amdgcn_mfma_f32_16x16x32_bf16(a, bh, acchx, 0, 0, 0);
            }
        }
        // ---- phase H: k in [512, 1536), A = hdec_prev bf16 ----
        {
            const unsigned short* ap = hbp + (size_t)(b_base + l15) * U_ + 8 * lk;
            #pragma unroll 4
            for (int ks = 0; ks < U_ / 32; ++ks) {
                const bf16x8 a  = ldb16(ap + 32 * ks);
                const bf16x8 bz = ldb16(bpz + D_ + 32 * ks);
                const bf16x8 br = ldb16(bpr + D_ + 32 * ks);
                const bf16x8 bh = ldb16(bph + D_ + 32 * ks);
                accz  = __builtin_amdgcn_mfma_f32_16x16x32_bf16(a, bz, accz,  0, 0, 0);
                accr  = __builtin_amdgcn_mfma_f32_16x16x32_bf16(a, br, accr,  0, 0, 0);
                acchr = __builtin_amdgcn_mfma_f32_16x16x32_bf16(a, bh, acchr, 0, 0, 0);
            }
        }

        // ---- epilogue: gates, blend, pre-decay for next step ----
        #pragma unroll
        for (int q = 0; q < 4; ++q) {
            const int b = b_base + lk * 4 + q;
            const float z  = 1.0f / (1.0f + expf(-(accz[q]  + bz_s)));
            const float r  = 1.0f / (1.0f + expf(-(accr[q]  + br_s)));
            const float hh = tanhf(acchx[q] + ibh + r * (acchr[q] + rbh));
            const float hdp = hfp[(size_t)b * U_ + u];
            const float hn  = z * hdp + (1.0f - z) * hh;
            if (t == T_ - 1) {
                out[(size_t)b * U_ + u] = hn;
            } else {
                const float dn = 1.0f / logf(E_CONST + dts[b * T_ + t + 1]);
                const float hd = hn * dn;
                hfn[(size_t)b * U_ + u] = hd;
                hbn[(size_t)b * U_ + u] = f2bf(hd);
            }
        }

        if (t != T_ - 1) grid.sync();
    }
}

extern "C" void kernel_launch(void* const* d_in, const int* in_sizes, int n_in,
                              void* d_out, int out_size, void* d_ws, size_t ws_size,
                              hipStream_t stream) {
    const float* seq = (const float*)d_in[0];
    const float* dts = (const float*)d_in[1];
    const float* Wk  = (const float*)d_in[2];
    const float* Wr  = (const float*)d_in[3];
    const float* ib  = (const float*)d_in[4];
    const float* rb  = (const float*)d_in[5];
    float* out = (float*)d_out;

    char* wsb = (char*)d_ws;
    // ws layout (bytes):
    //   [0, 9437184)            WcatT bf16 [3072][1536]
    //   [9437184, 9699328)      hdecb ping [128][1024] bf16
    //   [9699328, 9961472)      hdecb pong
    //   [9961472, 10485760)     hdecf ping [128][1024] fp32
    //   [10485760, 11010048)    hdecf pong
    unsigned short* wcat = (unsigned short*)(wsb);
    unsigned short* hb0 = (unsigned short*)(wsb + 9437184);
    unsigned short* hb1 = (unsigned short*)(wsb + 9699328);
    float* hf0 = (float*)(wsb + 9961472);
    float* hf1 = (float*)(wsb + 10485760);

    // h0 = 0 in the ping buffers (read at t=0); re-zeroed every replay.
    hipMemsetAsync(hb0, 0, 262144, stream);
    hipMemsetAsync(hf0, 0, 524288, stream);

    wprep<<<dim3(K_TOT / 32, N3U / 32), dim3(32, 8), 0, stream>>>(Wk, Wr, wcat);

    void* args[] = {
        (void*)&seq, (void*)&dts, (void*)&wcat, (void*)&ib, (void*)&rb,
        (void*)&hb0, (void*)&hf0, (void*)&hb1, (void*)&hf1, (void*)&out
    };
    hipLaunchCooperativeKernel((void*)tgru_persist, dim3(64), dim3(512),
                               args, 0, stream);
}

// Round 5
// 10144.332 us; speedup vs baseline: 1.4153x; 1.4153x over previous
//
#include <hip/hip_runtime.h>
#include <hip/hip_cooperative_groups.h>
#include <math.h>

namespace {
constexpr int B_ = 128;
constexpr int T_ = 256;
constexpr int D_ = 512;
constexpr int U_ = 1024;
constexpr int N3U = 3 * U_;        // 3072
constexpr int K_TOT = D_ + U_;     // 1536
constexpr int NHB = 64;            // h-blocks (one u-tile of 16 each)
constexpr int NXB = 192;           // x-blocks (8 tiles each, 1 per wave)
constexpr int LDS_BYTES = 48 * 1024 * 2;   // 96 KiB: 3 gates x 16 u x 1024 k bf16
}

#define E_CONST 2.71828182845904523536f

using bf16x8 = __attribute__((ext_vector_type(8))) short;
using f32x4  = __attribute__((ext_vector_type(4))) float;

__device__ inline unsigned short f2bf(float f) {
    union { float f; unsigned int u; } a; a.f = f;
    unsigned int u = a.u;
    return (unsigned short)((u + 0x7FFFu + ((u >> 16) & 1u)) >> 16);  // RNE
}

__device__ inline bf16x8 ldb16(const unsigned short* p) {
    return *reinterpret_cast<const bf16x8*>(p);
}

__device__ inline bf16x8 cvt8(const float* src) {
    float v[8];
    *reinterpret_cast<float4*>(&v[0]) = *reinterpret_cast<const float4*>(src);
    *reinterpret_cast<float4*>(&v[4]) = *reinterpret_cast<const float4*>(src + 4);
    bf16x8 r;
    #pragma unroll
    for (int j = 0; j < 8; ++j) r[j] = (short)f2bf(v[j]);
    return r;
}

// ---- one-time prep: WcatT[n][k] = bf16( k<512 ? Wk[k][n] : Wr[k-512][n] ) ----
__global__ void wprep(const float* __restrict__ Wk, const float* __restrict__ Wr,
                      unsigned short* __restrict__ WcatT) {
    __shared__ unsigned short S[32][33];
    const int kb = blockIdx.x * 32;
    const int nb = blockIdx.y * 32;
    const int tx = threadIdx.x;
    const int ty = threadIdx.y;
    #pragma unroll
    for (int j = 0; j < 4; ++j) {
        const int r = ty + 8 * j;
        const int k = kb + r;
        const int n = nb + tx;
        const float v = (k < D_) ? Wk[(size_t)k * N3U + n]
                                 : Wr[(size_t)(k - D_) * N3U + n];
        S[tx][r] = f2bf(v);
    }
    __syncthreads();
    #pragma unroll
    for (int j = 0; j < 4; ++j) {
        const int r = ty + 8 * j;
        WcatT[(size_t)(nb + r) * K_TOT + kb + tx] = S[r][tx];
    }
}

// ---- persistent kernel: 64 h-blocks (LDS-resident weights) + 192 x-blocks ----
// 512 threads = 8 waves per block. Dynamic LDS 96 KiB (h-blocks only use it).
__global__ __launch_bounds__(512, 2) void tgru_persist2(
    const float* __restrict__ seq,            // [B,T,D] fp32
    const float* __restrict__ dts,            // [B,T]
    const unsigned short* __restrict__ WcatT, // [3072][1536] bf16
    const float* __restrict__ ib,             // [3U]
    const float* __restrict__ rb,             // [3U]
    unsigned short* hb0, float* hf0,          // ping: h*dec (bf16 / fp32)
    unsigned short* hb1, float* hf1,          // pong
    float* xb0, float* xb1,                   // x_proj dbuf, fragment layout
    float* __restrict__ out)                  // [B,U]
{
    extern __shared__ char lds[];
    cooperative_groups::grid_group grid = cooperative_groups::this_grid();

    const int tid  = threadIdx.x;
    const int lane = tid & 63;
    const int w    = tid >> 6;     // wave 0..7
    const int l15  = lane & 15;
    const int lk   = lane >> 4;    // 0..3
    const int bid  = blockIdx.x;

    if (bid < NHB) {
        // ================= h-block: u-tile 16, all 128 b, K=1024 =================
        const int ub = bid;
        const int u  = ub * 16 + l15;
        const int b0 = w * 16;

        // Stage recurrent weights (k in [512,1536)) into LDS, XOR-swizzled.
        // Element (c=g*16+r, kk) at byte (c*2048 + 2*kk) ^ ((c&7)<<4).
        for (int i = tid; i < 48 * 1024; i += 512) {
            const int c  = i >> 10;         // 0..47
            const int kk = i & 1023;
            const int g  = c >> 4;
            const int r  = c & 15;
            const unsigned short v =
                WcatT[(size_t)(g * U_ + ub * 16 + r) * K_TOT + D_ + kk];
            const int byte = (i * 2) ^ ((c & 7) << 4);
            *reinterpret_cast<unsigned short*>(lds + byte) = v;
        }
        __syncthreads();

        const float bz_s = ib[u]          + rb[u];
        const float br_s = ib[U_ + u]     + rb[U_ + u];
        const float ibh  = ib[2 * U_ + u];
        const float rbh  = rb[2 * U_ + u];
        const int swz = (l15 & 7) << 4;
        // per-gate LDS base (bytes, pre-XOR): row (g*16+l15), col 16*lk
        int lbase[3];
        #pragma unroll
        for (int g = 0; g < 3; ++g)
            lbase[g] = ((g * 16 + l15) << 11) + 16 * lk;

        grid.sync();    // xbuf[0] ready

        for (int t = 0; t < T_; ++t) {
            const unsigned short* hbp = (t & 1) ? hb1 : hb0;
            const float*          hfp = (t & 1) ? hf1 : hf0;
            unsigned short*       hbn = (t & 1) ? hb0 : hb1;
            float*                hfn = (t & 1) ? hf0 : hf1;
            const float*          xbr = (t & 1) ? xb1 : xb0;

            f32x4 az = {0.f,0.f,0.f,0.f}, ar = {0.f,0.f,0.f,0.f}, ah = {0.f,0.f,0.f,0.f};
            const unsigned short* ap = hbp + (size_t)(b0 + l15) * U_ + 8 * lk;

            #pragma unroll 4
            for (int ks = 0; ks < 32; ++ks) {
                const bf16x8 a = ldb16(ap + 32 * ks);
                const bf16x8 fz = *reinterpret_cast<const bf16x8*>(
                    lds + ((lbase[0] + 64 * ks) ^ swz));
                const bf16x8 fr = *reinterpret_cast<const bf16x8*>(
                    lds + ((lbase[1] + 64 * ks) ^ swz));
                const bf16x8 fh = *reinterpret_cast<const bf16x8*>(
                    lds + ((lbase[2] + 64 * ks) ^ swz));
                az = __builtin_amdgcn_mfma_f32_16x16x32_bf16(a, fz, az, 0, 0, 0);
                ar = __builtin_amdgcn_mfma_f32_16x16x32_bf16(a, fr, ar, 0, 0, 0);
                ah = __builtin_amdgcn_mfma_f32_16x16x32_bf16(a, fh, ah, 0, 0, 0);
            }

            // x_proj fragments (same C layout, coalesced f32x4)
            const f32x4 xz4 = *reinterpret_cast<const f32x4*>(
                xbr + ((size_t)((0 * 64 + ub) * 8 + w) * 64 + lane) * 4);
            const f32x4 xr4 = *reinterpret_cast<const f32x4*>(
                xbr + ((size_t)((1 * 64 + ub) * 8 + w) * 64 + lane) * 4);
            const f32x4 xh4 = *reinterpret_cast<const f32x4*>(
                xbr + ((size_t)((2 * 64 + ub) * 8 + w) * 64 + lane) * 4);

            #pragma unroll
            for (int q = 0; q < 4; ++q) {
                const int b = b0 + lk * 4 + q;
                const float z  = 1.0f / (1.0f + expf(-(az[q] + xz4[q] + bz_s)));
                const float r  = 1.0f / (1.0f + expf(-(ar[q] + xr4[q] + br_s)));
                const float hh = tanhf(xh4[q] + ibh + r * (ah[q] + rbh));
                const float hdp = hfp[(size_t)b * U_ + u];
                const float hn  = z * hdp + (1.0f - z) * hh;
                if (t == T_ - 1) {
                    out[(size_t)b * U_ + u] = hn;
                } else {
                    const float dn = 1.0f / logf(E_CONST + dts[b * T_ + t + 1]);
                    const float hd = hn * dn;
                    hfn[(size_t)b * U_ + u] = hd;
                    hbn[(size_t)b * U_ + u] = f2bf(hd);
                }
            }

            if (t != T_ - 1) grid.sync();
        }
    } else {
        // ================= x-block: x_proj for step t+1 (K=512) =================
        const int xid   = bid - NHB;
        const int gtile = xid * 8 + w;      // 0..1535
        const int bt    = gtile & 7;
        const int nt    = gtile >> 3;       // 0..191
        const int b     = bt * 16 + l15;
        const int n     = nt * 16 + l15;
        const unsigned short* bp = WcatT + (size_t)n * K_TOT + 8 * lk;

        // prologue: x_proj for t=0 into xb0
        {
            const float* ap = seq + (size_t)b * (T_ * D_) + 8 * lk;
            f32x4 acc = {0.f,0.f,0.f,0.f};
            #pragma unroll 4
            for (int ks = 0; ks < 16; ++ks)
                acc = __builtin_amdgcn_mfma_f32_16x16x32_bf16(
                    cvt8(ap + 32 * ks), ldb16(bp + 32 * ks), acc, 0, 0, 0);
            *reinterpret_cast<f32x4*>(xb0 + ((size_t)gtile * 64 + lane) * 4) = acc;
        }
        grid.sync();

        for (int t = 0; t < T_; ++t) {
            if (t != T_ - 1) {
                float* xbw = (t & 1) ? xb0 : xb1;   // buffer for step t+1
                const float* ap = seq + (size_t)b * (T_ * D_)
                                      + (size_t)(t + 1) * D_ + 8 * lk;
                f32x4 acc = {0.f,0.f,0.f,0.f};
                #pragma unroll 4
                for (int ks = 0; ks < 16; ++ks)
                    acc = __builtin_amdgcn_mfma_f32_16x16x32_bf16(
                        cvt8(ap + 32 * ks), ldb16(bp + 32 * ks), acc, 0, 0, 0);
                *reinterpret_cast<f32x4*>(xbw + ((size_t)gtile * 64 + lane) * 4) = acc;
                grid.sync();
            }
        }
    }
}

extern "C" void kernel_launch(void* const* d_in, const int* in_sizes, int n_in,
                              void* d_out, int out_size, void* d_ws, size_t ws_size,
                              hipStream_t stream) {
    const float* seq = (const float*)d_in[0];
    const float* dts = (const float*)d_in[1];
    const float* Wk  = (const float*)d_in[2];
    const float* Wr  = (const float*)d_in[3];
    const float* ib  = (const float*)d_in[4];
    const float* rb  = (const float*)d_in[5];
    float* out = (float*)d_out;

    char* wsb = (char*)d_ws;
    // ws layout (bytes):
    //   [0,        9437184)   WcatT bf16 [3072][1536]
    //   [9437184,  9699328)   hdecb ping
    //   [9699328,  9961472)   hdecb pong
    //   [9961472, 10485760)   hdecf ping
    //   [10485760,11010048)   hdecf pong
    //   [11010048,12582912)   xbuf0 fp32 [1536 tiles][64 lanes][4]
    //   [12582912,14155776)   xbuf1
    unsigned short* wcat = (unsigned short*)(wsb);
    unsigned short* hb0 = (unsigned short*)(wsb + 9437184);
    unsigned short* hb1 = (unsigned short*)(wsb + 9699328);
    float* hf0 = (float*)(wsb + 9961472);
    float* hf1 = (float*)(wsb + 10485760);
    float* xb0 = (float*)(wsb + 11010048);
    float* xb1 = (float*)(wsb + 12582912);

    hipMemsetAsync(hb0, 0, 262144, stream);
    hipMemsetAsync(hf0, 0, 524288, stream);

    wprep<<<dim3(K_TOT / 32, N3U / 32), dim3(32, 8), 0, stream>>>(Wk, Wr, wcat);

    hipFuncSetAttribute((const void*)tgru_persist2,
                        hipFuncAttributeMaxDynamicSharedMemorySize, LDS_BYTES);

    void* args[] = {
        (void*)&seq, (void*)&dts, (void*)&wcat, (void*)&ib, (void*)&rb,
        (void*)&hb0, (void*)&hf0, (void*)&hb1, (void*)&hf1,
        (void*)&xb0, (void*)&xb1, (void*)&out
    };
    hipLaunchCooperativeKernel((void*)tgru_persist2, dim3(NHB + NXB), dim3(512),
                               args, LDS_BYTES, stream);
}

// Round 6
// 6421.030 us; speedup vs baseline: 2.2360x; 1.5799x over previous
//
#include <hip/hip_runtime.h>
#include <hip/hip_cooperative_groups.h>
#include <math.h>

namespace {
constexpr int B_ = 128;
constexpr int T_ = 256;
constexpr int D_ = 512;
constexpr int U_ = 1024;
constexpr int N3U = 3 * U_;        // 3072
constexpr int K_TOT = D_ + U_;     // 1536
constexpr int NBG = 4;             // b-groups (M=32 each)
constexpr int NUB = 64;            // u-blocks per group (16 u each)
constexpr int WROWS = 48;          // 3 gates x 16 u
constexpr int ROWB = 3088;         // LDS row stride bytes: (1536+8)*2
constexpr int EXCH_OFF = WROWS * ROWB;          // 148224
constexpr int LDS_BYTES = EXCH_OFF + 6 * 2048;  // 160512
}

#define E_CONST 2.71828182845904523536f

using bf16x8 = __attribute__((ext_vector_type(8))) short;
using f32x4  = __attribute__((ext_vector_type(4))) float;

__device__ inline unsigned short f2bf(float f) {
    union { float f; unsigned int u; } a; a.f = f;
    unsigned int u = a.u;
    return (unsigned short)((u + 0x7FFFu + ((u >> 16) & 1u)) >> 16);  // RNE
}

__device__ inline bf16x8 cvt8(const float* src) {
    float v[8];
    *reinterpret_cast<float4*>(&v[0]) = *reinterpret_cast<const float4*>(src);
    *reinterpret_cast<float4*>(&v[4]) = *reinterpret_cast<const float4*>(src + 4);
    bf16x8 r;
    #pragma unroll
    for (int j = 0; j < 8; ++j) r[j] = (short)f2bf(v[j]);
    return r;
}

// ---- one-time prep: WcatT[n][k] = bf16( k<512 ? Wk[k][n] : Wr[k-512][n] ) ----
__global__ void wprep(const float* __restrict__ Wk, const float* __restrict__ Wr,
                      unsigned short* __restrict__ WcatT) {
    __shared__ unsigned short S[32][33];
    const int kb = blockIdx.x * 32;
    const int nb = blockIdx.y * 32;
    const int tx = threadIdx.x;
    const int ty = threadIdx.y;
    #pragma unroll
    for (int j = 0; j < 4; ++j) {
        const int r = ty + 8 * j;
        const int k = kb + r;
        const int n = nb + tx;
        const float v = (k < D_) ? Wk[(size_t)k * N3U + n]
                                 : Wr[(size_t)(k - D_) * N3U + n];
        S[tx][r] = f2bf(v);
    }
    __syncthreads();
    #pragma unroll
    for (int j = 0; j < 4; ++j) {
        const int r = ty + 8 * j;
        WcatT[(size_t)(nb + r) * K_TOT + kb + tx] = S[r][tx];
    }
}

// ---- persistent kernel, flag-based sync (no grid.sync in steady state) ----
// 256 blocks = 4 b-groups x 64 u-blocks; 512 threads = 8 waves.
// Waves 0-5: (bt = w&1, gate g = w>>1) GEMM over full K=1536, LDS weights.
// Waves 6-7: (bt = w-6) decay prefetch + gate epilogue; fp32 h*dec in registers.
__global__ __launch_bounds__(512) void tgru_flags(
    const float* __restrict__ seq,            // [B,T,D] fp32
    const float* __restrict__ dts,            // [B,T]
    const unsigned short* __restrict__ WcatT, // [3072][1536] bf16
    const float* __restrict__ ib,             // [3U]
    const float* __restrict__ rb,             // [3U]
    unsigned short* hbA,                      // h*dec bf16 ping [128][1024]
    unsigned short* hbB,                      // pong
    unsigned int* cnt,                        // [NBG * 64] padded counters
    float* __restrict__ out)                  // [B,U]
{
    extern __shared__ char lds[];

    const int tid  = threadIdx.x;
    const int lane = tid & 63;
    const int w    = tid >> 6;
    const int l15  = lane & 15;
    const int lk   = lane >> 4;
    const int bid  = blockIdx.x;
    const int bg   = bid >> 6;    // 0..3
    const int ub   = bid & 63;    // 0..63
    const int u0   = ub * 16;

    // ---- stage weights: 48 rows x 1536 k into LDS (padded rows) ----
    for (int idx = tid; idx < WROWS * 192; idx += 512) {
        const int c = idx / 192;          // row 0..47
        const int o = idx % 192;          // 16B chunk
        const unsigned short* src =
            WcatT + (size_t)((c >> 4) * U_ + u0 + (c & 15)) * K_TOT + o * 8;
        *reinterpret_cast<bf16x8*>(lds + (size_t)c * ROWB + o * 16) =
            *reinterpret_cast<const bf16x8*>(src);
    }
    __syncthreads();

    unsigned int* mycnt = cnt + bg * 64;   // 256 B apart
    char* exch = lds + EXCH_OFF;

    // epilogue-wave state
    float hreg[4] = {0.f, 0.f, 0.f, 0.f};  // h*dec fp32 (own patch), h0 = 0
    float bzs = 0.f, brs = 0.f, ibh_ = 0.f, rbh_ = 0.f;
    if (w >= 6) {
        const int u = u0 + l15;
        bzs  = ib[u] + rb[u];
        brs  = ib[U_ + u] + rb[U_ + u];
        ibh_ = ib[2 * U_ + u];
        rbh_ = rb[2 * U_ + u];
    }

    for (int t = 0; t < T_; ++t) {
        const unsigned short* hbp = (t & 1) ? hbB : hbA;
        unsigned short*       hbn = (t & 1) ? hbA : hbB;
        float decn[4];

        if (w < 6) {
            const int bt = w & 1;
            const int g  = w >> 1;
            const int b  = bg * 32 + bt * 16 + l15;
            const char* wrow = lds + (size_t)(g * 16 + l15) * ROWB + 16 * lk;

            f32x4 aX = {0.f, 0.f, 0.f, 0.f};
            f32x4 aH = {0.f, 0.f, 0.f, 0.f};

            // x-part (k in [0,512)) — independent of other blocks, hides sync
            const float* ap = seq + ((size_t)b * T_ + t) * D_ + 8 * lk;
            #pragma unroll 8
            for (int ks = 0; ks < 16; ++ks) {
                const bf16x8 a = cvt8(ap + 32 * ks);
                const bf16x8 bf = *reinterpret_cast<const bf16x8*>(wrow + 64 * ks);
                aX = __builtin_amdgcn_mfma_f32_16x16x32_bf16(a, bf, aX, 0, 0, 0);
            }

            // wait for h(t) from all 64 producers of this b-group
            if (t > 0) {
                const unsigned int tgt = (unsigned int)(64 * t);
                int guard = 0;
                while (__hip_atomic_load(mycnt, __ATOMIC_RELAXED,
                                         __HIP_MEMORY_SCOPE_AGENT) < tgt) {
                    if (++guard > (1 << 18)) break;   // safety: no container hang
                }
                __builtin_amdgcn_fence(__ATOMIC_ACQUIRE, "agent");
            }

            // h-part (k in [512,1536))
            const unsigned short* hp = hbp + (size_t)b * U_ + 8 * lk;
            #pragma unroll 8
            for (int ks = 0; ks < 32; ++ks) {
                const bf16x8 a = *reinterpret_cast<const bf16x8*>(hp + 32 * ks);
                const bf16x8 bf = *reinterpret_cast<const bf16x8*>(
                    wrow + 1024 + 64 * ks);
                aH = __builtin_amdgcn_mfma_f32_16x16x32_bf16(a, bf, aH, 0, 0, 0);
            }

            *reinterpret_cast<f32x4*>(exch + w * 2048 + lane * 16) = aX;
            *reinterpret_cast<f32x4*>(exch + w * 2048 + 1024 + lane * 16) = aH;
        } else {
            // decay prefetch for t+1 (latency hidden behind waves 0-5 GEMM)
            const int bt = w - 6;
            const int tn = (t < T_ - 1) ? t + 1 : t;
            #pragma unroll
            for (int q = 0; q < 4; ++q) {
                const int b = bg * 32 + bt * 16 + lk * 4 + q;
                decn[q] = 1.0f / logf(E_CONST + dts[b * T_ + tn]);
            }
        }

        __syncthreads();

        if (w >= 6) {
            const int bt = w - 6;
            const f32x4 zX = *reinterpret_cast<f32x4*>(exch + (0 + bt) * 2048 + lane * 16);
            const f32x4 zH = *reinterpret_cast<f32x4*>(exch + (0 + bt) * 2048 + 1024 + lane * 16);
            const f32x4 rX = *reinterpret_cast<f32x4*>(exch + (2 + bt) * 2048 + lane * 16);
            const f32x4 rH = *reinterpret_cast<f32x4*>(exch + (2 + bt) * 2048 + 1024 + lane * 16);
            const f32x4 hX = *reinterpret_cast<f32x4*>(exch + (4 + bt) * 2048 + lane * 16);
            const f32x4 hH = *reinterpret_cast<f32x4*>(exch + (4 + bt) * 2048 + 1024 + lane * 16);
            const int u = u0 + l15;
            #pragma unroll
            for (int q = 0; q < 4; ++q) {
                const int b = bg * 32 + bt * 16 + lk * 4 + q;
                const float z  = 1.0f / (1.0f + expf(-(zX[q] + zH[q] + bzs)));
                const float r  = 1.0f / (1.0f + expf(-(rX[q] + rH[q] + brs)));
                const float hh = tanhf(hX[q] + ibh_ + r * (hH[q] + rbh_));
                const float hn = z * hreg[q] + (1.0f - z) * hh;
                if (t == T_ - 1) {
                    out[(size_t)b * U_ + u] = hn;
                } else {
                    const float hd = hn * decn[q];
                    hreg[q] = hd;
                    hbn[(size_t)b * U_ + u] = f2bf(hd);
                }
            }
        }

        __syncthreads();   // epilogue stores drained (compiler waits vmcnt)

        if (tid == 0 && t < T_ - 1) {
            __builtin_amdgcn_fence(__ATOMIC_RELEASE, "agent");  // L2 -> L3 writeback
            __hip_atomic_fetch_add(mycnt, 1u, __ATOMIC_RELAXED,
                                   __HIP_MEMORY_SCOPE_AGENT);
        }
    }
}

extern "C" void kernel_launch(void* const* d_in, const int* in_sizes, int n_in,
                              void* d_out, int out_size, void* d_ws, size_t ws_size,
                              hipStream_t stream) {
    const float* seq = (const float*)d_in[0];
    const float* dts = (const float*)d_in[1];
    const float* Wk  = (const float*)d_in[2];
    const float* Wr  = (const float*)d_in[3];
    const float* ib  = (const float*)d_in[4];
    const float* rb  = (const float*)d_in[5];
    float* out = (float*)d_out;

    char* wsb = (char*)d_ws;
    // ws layout (bytes):
    //   [0,       9437184)   WcatT bf16 [3072][1536]
    //   [9437184, 9699328)   hbA bf16 [128][1024]
    //   [9699328, 9961472)   hbB
    //   [9961472, 9962496)   cnt  (4 groups x 256 B)
    unsigned short* wcat = (unsigned short*)(wsb);
    unsigned short* hbA  = (unsigned short*)(wsb + 9437184);
    unsigned short* hbB  = (unsigned short*)(wsb + 9699328);
    unsigned int*   cnt  = (unsigned int*)(wsb + 9961472);

    // per-launch reset (graph-captured, deterministic)
    hipMemsetAsync(hbA, 0, 262144, stream);
    hipMemsetAsync(cnt, 0, 1024, stream);

    wprep<<<dim3(K_TOT / 32, N3U / 32), dim3(32, 8), 0, stream>>>(Wk, Wr, wcat);

    hipFuncSetAttribute((const void*)tgru_flags,
                        hipFuncAttributeMaxDynamicSharedMemorySize, LDS_BYTES);

    void* args[] = {
        (void*)&seq, (void*)&dts, (void*)&wcat, (void*)&ib, (void*)&rb,
        (void*)&hbA, (void*)&hbB, (void*)&cnt, (void*)&out
    };
    hipLaunchCooperativeKernel((void*)tgru_flags, dim3(NBG * NUB), dim3(512),
                               args, LDS_BYTES, stream);
}

// Round 7
// 3264.961 us; speedup vs baseline: 4.3975x; 1.9666x over previous
//
#include <hip/hip_runtime.h>
#include <math.h>

namespace {
constexpr int B_ = 128;
constexpr int T_ = 256;
constexpr int D_ = 512;
constexpr int U_ = 1024;
constexpr int N3U = 3 * U_;        // 3072
constexpr int K_TOT = D_ + U_;     // 1536
constexpr int NBG = 4;             // b-groups (M=32 each)
constexpr int NUB = 64;            // u-blocks per group (16 u each)
constexpr int WROWS = 48;          // 3 gates x 16 u
constexpr int ROWB = 3088;         // LDS row stride bytes: (1536+8)*2
constexpr int EXCH_OFF = WROWS * ROWB;          // 148224
constexpr int LDS_BYTES = EXCH_OFF + 6 * 2048;  // 160512
constexpr int POLL_LIM = 1 << 20;
}

#define E_CONST 2.71828182845904523536f

using bf16x8 = __attribute__((ext_vector_type(8))) short;
using f32x4  = __attribute__((ext_vector_type(4))) float;

__device__ inline unsigned short f2bf(float f) {
    union { float f; unsigned int u; } a; a.f = f;
    unsigned int u = a.u;
    return (unsigned short)((u + 0x7FFFu + ((u >> 16) & 1u)) >> 16);  // RNE
}

__device__ inline bf16x8 cvt8(const float* src) {
    float v[8];
    *reinterpret_cast<float4*>(&v[0]) = *reinterpret_cast<const float4*>(src);
    *reinterpret_cast<float4*>(&v[4]) = *reinterpret_cast<const float4*>(src + 4);
    bf16x8 r;
    #pragma unroll
    for (int j = 0; j < 8; ++j) r[j] = (short)f2bf(v[j]);
    return r;
}

// ---- one-time prep: WcatT[n][k] = bf16( k<512 ? Wk[k][n] : Wr[k-512][n] ) ----
__global__ void wprep(const float* __restrict__ Wk, const float* __restrict__ Wr,
                      unsigned short* __restrict__ WcatT) {
    __shared__ unsigned short S[32][33];
    const int kb = blockIdx.x * 32;
    const int nb = blockIdx.y * 32;
    const int tx = threadIdx.x;
    const int ty = threadIdx.y;
    #pragma unroll
    for (int j = 0; j < 4; ++j) {
        const int r = ty + 8 * j;
        const int k = kb + r;
        const int n = nb + tx;
        const float v = (k < D_) ? Wk[(size_t)k * N3U + n]
                                 : Wr[(size_t)(k - D_) * N3U + n];
        S[tx][r] = f2bf(v);
    }
    __syncthreads();
    #pragma unroll
    for (int j = 0; j < 4; ++j) {
        const int r = ty + 8 * j;
        WcatT[(size_t)(nb + r) * K_TOT + kb + tx] = S[r][tx];
    }
}

// ---- persistent kernel, per-producer flag sync (no RMW, no wbl2) ----
// 256 blocks = 4 b-groups x 64 u-blocks; 512 threads = 8 waves.
// Waves 0-5: (bt = w&1, gate g = w>>1) GEMM over K=1536 from LDS weights.
// Wave 6: epilogue half. Wave 7: poller + epilogue half.
__global__ __launch_bounds__(512) void tgru_flags2(
    const float* __restrict__ seq,            // [B,T,D] fp32
    const float* __restrict__ dts,            // [B,T]
    const unsigned short* __restrict__ WcatT, // [3072][1536] bf16
    const float* __restrict__ ib,             // [3U]
    const float* __restrict__ rb,             // [3U]
    unsigned short* hbA,                      // h*dec bf16 (holds h(even t))
    unsigned short* hbB,                      // holds h(odd t)
    unsigned int* flags,                      // [NBG*64] x 16 u32 (64B lines)
    float* __restrict__ out)                  // [B,U]
{
    extern __shared__ char lds[];

    const int tid  = threadIdx.x;
    const int lane = tid & 63;
    const int w    = tid >> 6;
    const int l15  = lane & 15;
    const int lk   = lane >> 4;
    const int bid  = blockIdx.x;
    const int bg   = bid >> 6;    // 0..3
    const int ub   = bid & 63;    // 0..63
    const int u0   = ub * 16;

    // ---- stage weights: 48 rows x 1536 k into LDS (padded rows) ----
    for (int idx = tid; idx < WROWS * 192; idx += 512) {
        const int c = idx / 192;          // row 0..47
        const int o = idx % 192;          // 16B chunk
        const unsigned short* src =
            WcatT + (size_t)((c >> 4) * U_ + u0 + (c & 15)) * K_TOT + o * 8;
        *reinterpret_cast<bf16x8*>(lds + (size_t)c * ROWB + o * 16) =
            *reinterpret_cast<const bf16x8*>(src);
    }
    __syncthreads();

    float* exf = reinterpret_cast<float*>(lds + EXCH_OFF);

    // ---- epilogue-wave constants ----
    const int up = lane & 7;          // u-pair index
    const int rg = lane >> 3;         // 0..7 row-group
    float bzs[2], brs[2], ibh_[2], rbh_[2];
    float hreg[2][2] = {{0.f, 0.f}, {0.f, 0.f}};
    if (w >= 6) {
        #pragma unroll
        for (int f = 0; f < 2; ++f) {
            const int u = u0 + 2 * up + f;
            bzs[f]  = ib[u] + rb[u];
            brs[f]  = ib[U_ + u] + rb[U_ + u];
            ibh_[f] = ib[2 * U_ + u];
            rbh_[f] = rb[2 * U_ + u];
        }
    }
    unsigned int* myflag = flags + ((bg << 6) + ub) * 16 + (w - 6);

    for (int t = 0; t < T_; ++t) {
        const unsigned short* hbp = (t & 1) ? hbB : hbA;   // h(t)
        unsigned short*       hbn = (t & 1) ? hbA : hbB;   // h(t+1)
        float decn[2];

        f32x4 aX = {0.f, 0.f, 0.f, 0.f};
        f32x4 aH = {0.f, 0.f, 0.f, 0.f};
        const char* wrow = lds + (size_t)((w >> 1) * 16 + l15) * ROWB + 16 * lk;
        const int bgemm = bg * 32 + (w & 1) * 16 + l15;

        if (w < 6) {
            // x-part (k in [0,512)) — overlaps wave 7's poll
            const float* ap = seq + ((size_t)bgemm * T_ + t) * D_ + 8 * lk;
            #pragma unroll 8
            for (int ks = 0; ks < 16; ++ks) {
                const bf16x8 a = cvt8(ap + 32 * ks);
                const bf16x8 bf = *reinterpret_cast<const bf16x8*>(wrow + 64 * ks);
                aX = __builtin_amdgcn_mfma_f32_16x16x32_bf16(a, bf, aX, 0, 0, 0);
            }
        } else {
            // decay prefetch for t+1
            const int tn = (t < T_ - 1) ? t + 1 : t;
            #pragma unroll
            for (int e = 0; e < 2; ++e) {
                const int b = bg * 32 + (w - 6) * 16 + rg * 2 + e;
                decn[e] = 1.0f / logf(E_CONST + dts[b * T_ + tn]);
            }
            if (w == 7 && t > 0) {
                // poll all 64 producers x 2 halves of this b-group
                const unsigned long long* fl =
                    (const unsigned long long*)(flags + ((bg << 6) + lane) * 16);
                int guard = 0;
                for (;;) {
                    const unsigned long long v = __hip_atomic_load(
                        fl, __ATOMIC_RELAXED, __HIP_MEMORY_SCOPE_AGENT);
                    const int ok = ((unsigned)(v & 0xffffffffu) >= (unsigned)t) &&
                                   ((unsigned)(v >> 32)         >= (unsigned)t);
                    if (__all(ok)) break;
                    if (++guard > POLL_LIM) break;   // safety: no hang
                }
                __builtin_amdgcn_fence(__ATOMIC_ACQUIRE, "agent");  // inv L1+L2
            }
        }

        __syncthreads();   // B1: h(t) visible, caches invalidated

        if (w < 6) {
            if (t > 0) {
                const unsigned short* hp = hbp + (size_t)bgemm * U_ + 8 * lk;
                #pragma unroll 8
                for (int ks = 0; ks < 32; ++ks) {
                    const bf16x8 a = *reinterpret_cast<const bf16x8*>(hp + 32 * ks);
                    const bf16x8 bf = *reinterpret_cast<const bf16x8*>(
                        wrow + 1024 + 64 * ks);
                    aH = __builtin_amdgcn_mfma_f32_16x16x32_bf16(a, bf, aH, 0, 0, 0);
                }
            }
            *reinterpret_cast<f32x4*>(&exf[w * 512 + lane * 4]) = aX;
            *reinterpret_cast<f32x4*>(&exf[w * 512 + 256 + lane * 4]) = aH;
        }

        __syncthreads();   // B2: exchange ready

        if (w >= 6) {
            const int bt = w - 6;
            #pragma unroll
            for (int e = 0; e < 2; ++e) {
                const int bl  = rg * 2 + e;
                const int b   = bg * 32 + bt * 16 + bl;
                const int lkq = (bl >> 2) * 16;
                const int q   = bl & 3;
                float hn2[2];
                #pragma unroll
                for (int f = 0; f < 2; ++f) {
                    const int ul = 2 * up + f;
                    const int i0 = (0 * 2 + bt) * 512 + (lkq + ul) * 4 + q;
                    const int i1 = (1 * 2 + bt) * 512 + (lkq + ul) * 4 + q;
                    const int i2 = (2 * 2 + bt) * 512 + (lkq + ul) * 4 + q;
                    const float z  = 1.0f / (1.0f + expf(-(exf[i0] + exf[i0 + 256] + bzs[f])));
                    const float r  = 1.0f / (1.0f + expf(-(exf[i1] + exf[i1 + 256] + brs[f])));
                    const float hh = tanhf(exf[i2] + ibh_[f] + r * (exf[i2 + 256] + rbh_[f]));
                    hn2[f] = z * hreg[e][f] + (1.0f - z) * hh;
                }
                if (t == T_ - 1) {
                    *reinterpret_cast<float2*>(&out[(size_t)b * U_ + u0 + 2 * up]) =
                        make_float2(hn2[0], hn2[1]);
                } else {
                    const float hd0 = hn2[0] * decn[e];
                    const float hd1 = hn2[1] * decn[e];
                    hreg[e][0 + 0] = hd0;  // keep fp32 state in regs
                    hreg[e][1]     = hd1;
                    const unsigned int pk =
                        (unsigned int)f2bf(hd0) | ((unsigned int)f2bf(hd1) << 16);
                    __hip_atomic_store(
                        reinterpret_cast<unsigned int*>(&hbn[(size_t)b * U_ + u0 + 2 * up]),
                        pk, __ATOMIC_RELAXED, __HIP_MEMORY_SCOPE_AGENT);
                }
            }
            if (t < T_ - 1) {
                asm volatile("s_waitcnt vmcnt(0)" ::: "memory");  // h stores at L3
                if (lane == 0) {
                    __hip_atomic_store(myflag, (unsigned int)(t + 1),
                                       __ATOMIC_RELAXED, __HIP_MEMORY_SCOPE_AGENT);
                }
            }
        }
    }
}

extern "C" void kernel_launch(void* const* d_in, const int* in_sizes, int n_in,
                              void* d_out, int out_size, void* d_ws, size_t ws_size,
                              hipStream_t stream) {
    const float* seq = (const float*)d_in[0];
    const float* dts = (const float*)d_in[1];
    const float* Wk  = (const float*)d_in[2];
    const float* Wr  = (const float*)d_in[3];
    const float* ib  = (const float*)d_in[4];
    const float* rb  = (const float*)d_in[5];
    float* out = (float*)d_out;

    char* wsb = (char*)d_ws;
    // ws layout (bytes):
    //   [0,       9437184)   WcatT bf16 [3072][1536]
    //   [9437184, 9699328)   hbA bf16 [128][1024]  (h at even t; not pre-read)
    //   [9699328, 9961472)   hbB
    //   [9961472, 9977856)   flags: 256 blocks x 64 B
    unsigned short* wcat = (unsigned short*)(wsb);
    unsigned short* hbA  = (unsigned short*)(wsb + 9437184);
    unsigned short* hbB  = (unsigned short*)(wsb + 9699328);
    unsigned int*   flags = (unsigned int*)(wsb + 9961472);

    // flags must be 0 at start of every replay (monotonic within a launch)
    hipMemsetAsync(flags, 0, 16384, stream);

    wprep<<<dim3(K_TOT / 32, N3U / 32), dim3(32, 8), 0, stream>>>(Wk, Wr, wcat);

    hipFuncSetAttribute((const void*)tgru_flags2,
                        hipFuncAttributeMaxDynamicSharedMemorySize, LDS_BYTES);

    void* args[] = {
        (void*)&seq, (void*)&dts, (void*)&wcat, (void*)&ib, (void*)&rb,
        (void*)&hbA, (void*)&hbB, (void*)&flags, (void*)&out
    };
    hipLaunchCooperativeKernel((void*)tgru_flags2, dim3(NBG * NUB), dim3(512),
                               args, LDS_BYTES, stream);
}